// Round 9
// baseline (2204.670 us; speedup 1.0000x reference)
//
#include <hip/hip_runtime.h>
#include <math.h>

#define NPTS 8192
#define DIM 32
#define MAX_ITER 10
#define TOL 1e-4f
#define DAMP 0.5f
#define LOG2E 1.4426950408889634f
#define CXS 68   // fused row stride: [c(32) | x(32) | nc | keep | pad2]

// ---- scratch layout inside OUT_A (floats from A base); all consumed before k_apass2 ----
#define OFF_MSP    0u          // 32*33*8192 mean-shift partials
#define OFF_CXF    8650752u    // 8192*68 fused stream
#define OFF_CNEW   9207808u    // 8192*32
#define OFF_NX     9469952u    // 8192
#define OFF_PV     9478144u    // 32*8192 argmin partial val
#define OFF_PJ     9740288u    // 32*8192 argmin partial idx (int)
#define OFF_RKP   10002432u    // 32*8192 rank partials (int)
#define OFF_MSH   10264576u    // 16 maxshift slots (uint)
#define OFF_SCO   10264592u    // 8192 scores (int)
#define OFF_ORD   10272784u    // 8192 order (int)
// d_ws: ps softmax-sum partials (32*8192 floats = 1 MB; survives apass2's A writes)

// ---------------- init: cxf rows = [x | x | ||x||^2 | 0]; nx; zero scores/msh ------------
__global__ __launch_bounds__(256) void k_init(const float* __restrict__ x,
                                              float* __restrict__ cxf,
                                              float* __restrict__ nx,
                                              int* __restrict__ scores,
                                              unsigned int* __restrict__ msh) {
    int p = blockIdx.x * blockDim.x + threadIdx.x;
    const float4* xr = (const float4*)(x + (size_t)p * DIM);
    float* row = cxf + (size_t)p * CXS;
    float s = 0.f;
#pragma unroll
    for (int q = 0; q < 8; ++q) {
        float4 v = xr[q];
        ((float4*)row)[q] = v;       // c half
        ((float4*)row)[8 + q] = v;   // x half
        s += v.x * v.x + v.y * v.y + v.z * v.z + v.w * v.w;
    }
    row[64] = s;   // nc
    row[65] = 0.f; // keep placeholder
    nx[p] = s;
    scores[p] = 0;
    if (blockIdx.x == 0 && threadIdx.x < 16) msh[threadIdx.x] = 0u;
}

// ---------------- mean-shift partial pass: 1 row/lane, fused j-stream ----------------
// grid 1024 = 32 i-tiles(256 rows) x 32 j-splits(256 j). block 256 = 4 waves.
// 17 loads/jj at immediate offsets from one walking pointer; ~72 VALU/jj.
__global__ __launch_bounds__(256) void k_ms2(const float* __restrict__ x,
                                             const float* __restrict__ nx,
                                             const float* __restrict__ cxf,
                                             const float* __restrict__ sigma_p,
                                             float* __restrict__ P) {
    int t = threadIdx.x;
    int it = (int)blockIdx.x >> 5, js = (int)blockIdx.x & 31;
    int i = it * 256 + t;
    int jb = js * 256;

    float sg = sigma_p[0];
    float ng2 = -LOG2E / (2.f * sg * sg);   // w = exp2(ng2 * sq)

    float xi[DIM];
    {
        const float4* xr = (const float4*)(x + (size_t)i * DIM);
#pragma unroll
        for (int q = 0; q < 8; ++q) {
            float4 a = xr[q];
            xi[4 * q] = a.x; xi[4 * q + 1] = a.y; xi[4 * q + 2] = a.z; xi[4 * q + 3] = a.w;
        }
    }
    float nxi = nx[i];

    float acc[DIM];
#pragma unroll
    for (int d = 0; d < DIM; ++d) acc[d] = 0.f;
    float ws = 0.f;

    const float* row = cxf + (size_t)jb * CXS;

    for (int jj = 0; jj < 256; ++jj) {
        float w;
        {
            float a0 = 0.f, a1 = 0.f, a2 = 0.f, a3 = 0.f;
#pragma unroll
            for (int q = 0; q < 8; ++q) {
                float4 cv = ((const float4*)row)[q];
                a0 = fmaf(xi[4 * q + 0], cv.x, a0);
                a1 = fmaf(xi[4 * q + 1], cv.y, a1);
                a2 = fmaf(xi[4 * q + 2], cv.z, a2);
                a3 = fmaf(xi[4 * q + 3], cv.w, a3);
            }
            float ncj = row[64];
            float sq = fmaxf(fmaf(-2.f, (a0 + a1) + (a2 + a3), nxi + ncj), 0.f);
            w = __builtin_amdgcn_exp2f(ng2 * sq);
        }
        ws += w;
#pragma unroll
        for (int q = 0; q < 8; ++q) {
            float4 xv = ((const float4*)row)[8 + q];
            acc[4 * q + 0] = fmaf(w, xv.x, acc[4 * q + 0]);
            acc[4 * q + 1] = fmaf(w, xv.y, acc[4 * q + 1]);
            acc[4 * q + 2] = fmaf(w, xv.z, acc[4 * q + 2]);
            acc[4 * q + 3] = fmaf(w, xv.w, acc[4 * q + 3]);
        }
        row += CXS;
    }

    size_t base = ((size_t)js * 33) * NPTS + i;
#pragma unroll
    for (int d = 0; d < DIM; ++d) P[base + (size_t)d * NPTS] = acc[d];
    P[base + (size_t)32 * NPTS] = ws;
}

// ---------------- reduce partials -> c_new, maxshift ----------------
__global__ __launch_bounds__(256) void k_reduce(const float* __restrict__ P,
                                                const float* __restrict__ cxf,
                                                float* __restrict__ c_new,
                                                unsigned int* __restrict__ maxshift) {
    int i = blockIdx.x * 256 + threadIdx.x;
    float tot[33];
#pragma unroll
    for (int d = 0; d < 33; ++d) tot[d] = 0.f;
    for (int js = 0; js < 32; ++js) {
        size_t base = ((size_t)js * 33) * NPTS + i;
#pragma unroll
        for (int d = 0; d < 33; ++d) tot[d] += P[base + (size_t)d * NPTS];
    }
    float ws = tot[32];
    float inv = __builtin_amdgcn_rcpf(ws);
    inv = inv * (2.f - ws * inv);  // one NR step
    const float* co = cxf + (size_t)i * CXS;   // c half = current centroids
    float sh2 = 0.f;
    float ncv[DIM];
#pragma unroll
    for (int d = 0; d < DIM; ++d) {
        float v = tot[d] * inv;
        ncv[d] = v;
        float df = v - co[d];
        sh2 = fmaf(df, df, sh2);
    }
    float4* dst = (float4*)(c_new + (size_t)i * DIM);
#pragma unroll
    for (int q = 0; q < 8; ++q)
        dst[q] = make_float4(ncv[4 * q], ncv[4 * q + 1], ncv[4 * q + 2], ncv[4 * q + 3]);
    atomicMax(maxshift, __float_as_uint(__builtin_amdgcn_sqrtf(sh2)));
}

// ---------------- damped update of cxf c-half + nc (skipped when converged) --------------
__global__ __launch_bounds__(256) void k_update(float* __restrict__ cxf,
                                                const float* __restrict__ c_new,
                                                const unsigned int* __restrict__ maxshift) {
    if (__uint_as_float(*maxshift) < TOL) return;
    int i = blockIdx.x * 256 + threadIdx.x;
    float* row = cxf + (size_t)i * CXS;
    const float4* cn = (const float4*)(c_new + (size_t)i * DIM);
    float s = 0.f;
#pragma unroll
    for (int q = 0; q < 8; ++q) {
        float4 a = ((float4*)row)[q], b = cn[q];
        float4 r = make_float4(DAMP * a.x + (1.f - DAMP) * b.x,
                               DAMP * a.y + (1.f - DAMP) * b.y,
                               DAMP * a.z + (1.f - DAMP) * b.z,
                               DAMP * a.w + (1.f - DAMP) * b.w);
        ((float4*)row)[q] = r;
        s += r.x * r.x + r.y * r.y + r.z * r.z + r.w * r.w;
    }
    row[64] = s;
}

// ---------------- extract final centroids from cxf into OUT_C ----------------
__global__ __launch_bounds__(256) void k_extract(const float* __restrict__ cxf,
                                                 float* __restrict__ outc) {
    int g = blockIdx.x * 256 + threadIdx.x;   // one float4 each; 65536 total
    int rowi = g >> 3, q = g & 7;
    ((float4*)(outc + (size_t)rowi * DIM))[q] =
        ((const float4*)(cxf + (size_t)rowi * CXS))[q];
}

// ---------------- scores: 1 row/lane, fused stream, partial argmin ----------------
__global__ __launch_bounds__(256) void k_scores2(const float* __restrict__ x,
                                                 const float* __restrict__ nx,
                                                 const float* __restrict__ cxf,
                                                 float* __restrict__ pv,
                                                 int* __restrict__ pj) {
    int t = threadIdx.x;
    int it = (int)blockIdx.x >> 5, js = (int)blockIdx.x & 31;
    int p = it * 256 + t;
    int jb = js * 256;

    float xi[DIM];
    {
        const float4* xr = (const float4*)(x + (size_t)p * DIM);
#pragma unroll
        for (int q = 0; q < 8; ++q) {
            float4 a = xr[q];
            xi[4 * q] = a.x; xi[4 * q + 1] = a.y; xi[4 * q + 2] = a.z; xi[4 * q + 3] = a.w;
        }
    }
    float nxp = nx[p];

    const float* row = cxf + (size_t)jb * CXS;
    float bv = INFINITY;
    int bj = jb;
    for (int jj = 0; jj < 256; ++jj) {
        float a0 = 0.f, a1 = 0.f, a2 = 0.f, a3 = 0.f;
#pragma unroll
        for (int q = 0; q < 8; ++q) {
            float4 cv = ((const float4*)row)[q];
            a0 = fmaf(xi[4 * q + 0], cv.x, a0);
            a1 = fmaf(xi[4 * q + 1], cv.y, a1);
            a2 = fmaf(xi[4 * q + 2], cv.z, a2);
            a3 = fmaf(xi[4 * q + 3], cv.w, a3);
        }
        float ncj = row[64];
        float sq = fmaxf(fmaf(-2.f, (a0 + a1) + (a2 + a3), nxp + ncj), 0.f);
        if (sq < bv) { bv = sq; bj = jb + jj; }   // strict <: first min wins
        row += CXS;
    }
    pv[(size_t)js * NPTS + p] = bv;
    pj[(size_t)js * NPTS + p] = bj;
}

__global__ __launch_bounds__(256) void k_score_comb(const float* __restrict__ pv,
                                                    const int* __restrict__ pj,
                                                    int* __restrict__ scores) {
    int p = blockIdx.x * 256 + threadIdx.x;
    float bv = pv[p];
    int bj = pj[p];
    for (int js = 1; js < 32; ++js) {
        float v = pv[(size_t)js * NPTS + p];
        int j = pj[(size_t)js * NPTS + p];
        if (v < bv) { bv = v; bj = j; }  // ascending js: first global min
    }
    atomicAdd(&scores[bj], 1);
}

// ---------------- stable descending rank (split + combine) ----------------
__global__ __launch_bounds__(256) void k_rank_part(const int* __restrict__ scores,
                                                   int* __restrict__ rkp) {
    int t = threadIdx.x;
    int it = (int)blockIdx.x >> 5, js = (int)blockIdx.x & 31;
    int p = it * 256 + t;
    int sp = scores[p];
    int j0 = js * 256;
    int r = 0;
    for (int jj = 0; jj < 256; ++jj) {
        int sj = scores[j0 + jj];
        int j = j0 + jj;
        r += (sj > sp) || (sj == sp && j < p);
    }
    rkp[(size_t)js * NPTS + p] = r;
}

__global__ __launch_bounds__(256) void k_rank_comb(const int* __restrict__ rkp,
                                                   int* __restrict__ order) {
    int p = blockIdx.x * 256 + threadIdx.x;
    int r = 0;
    for (int js = 0; js < 32; ++js) r += rkp[(size_t)js * NPTS + p];
    order[r] = p;
}

// ---------------- greedy NMS scan (single block, ballot fast-forward) ----------------
__global__ __launch_bounds__(1024) void k_nms(const float* __restrict__ c,
                                              const int* __restrict__ order,
                                              const int* __restrict__ scores,
                                              const float* __restrict__ sigma_p,
                                              float* __restrict__ keep_out,
                                              float* __restrict__ cxf) {
    __shared__ int s_ord[NPTS];
    __shared__ unsigned char kp[NPTS];
    __shared__ int s_first[16];
    __shared__ int s_next;
    int t = threadIdx.x;
    for (int q = t; q < NPTS; q += 1024) { s_ord[q] = order[q]; kp[q] = 1; }
    __syncthreads();
    float sg = sigma_p[0];
    float thr2 = sg * sg;

    int k = 0;
    while (k < NPTS) {
        int cand = k + t;
        bool hit = (cand < NPTS) && (kp[s_ord[cand]] != 0);
        unsigned long long b = __ballot(hit);
        int wave = t >> 6;
        if ((t & 63) == 0)
            s_first[wave] = b ? (k + (wave << 6) + (__ffsll((unsigned long long)b) - 1))
                              : 0x7fffffff;
        __syncthreads();
        if (t == 0) {
            int mn = s_first[0];
            for (int w2 = 1; w2 < 16; ++w2) mn = min(mn, s_first[w2]);
            s_next = mn;
        }
        __syncthreads();
        int kf = s_next;
        if (kf == 0x7fffffff) { k += 1024; continue; }

        int idx = s_ord[kf];
        float ci[DIM];
        const float4* cr = (const float4*)(c + (size_t)idx * DIM);
#pragma unroll
        for (int q = 0; q < 8; ++q) {
            float4 v = cr[q];
            ci[4 * q] = v.x; ci[4 * q + 1] = v.y; ci[4 * q + 2] = v.z; ci[4 * q + 3] = v.w;
        }
#pragma unroll
        for (int m2 = 0; m2 < 8; ++m2) {
            int j = t + m2 * 1024;
            const float4* cj = (const float4*)(c + (size_t)j * DIM);
            float sq = 0.f;
#pragma unroll
            for (int q = 0; q < 8; ++q) {
                float4 v = cj[q];
                float e0 = v.x - ci[4 * q], e1 = v.y - ci[4 * q + 1];
                float e2 = v.z - ci[4 * q + 2], e3 = v.w - ci[4 * q + 3];
                sq += e0 * e0 + e1 * e1 + e2 * e2 + e3 * e3;
            }
            if (j != idx && sq < thr2) kp[j] = 0;
        }
        __syncthreads();
        if (t == 0) kp[idx] = (scores[idx] > 0) ? 1 : 0;
        __syncthreads();
        k = kf + 1;
    }
    __syncthreads();
    for (int q = t; q < NPTS; q += 1024) {
        float kv = kp[q] ? 1.0f : 0.0f;
        keep_out[q] = kv;
        cxf[(size_t)q * CXS + 65] = kv;
    }
}

// ---------------- assignment pass 1: 1 row/lane, fused stream (M == 0) -------------------
__global__ __launch_bounds__(256) void k_apass1(const float* __restrict__ x,
                                                const float* __restrict__ nx,
                                                const float* __restrict__ cxf,
                                                float* __restrict__ ps) {
    int t = threadIdx.x;
    int it = (int)blockIdx.x >> 5, js = (int)blockIdx.x & 31;
    int p = it * 256 + t;
    int jb = js * 256;

    float xi[DIM];
    {
        const float4* xr = (const float4*)(x + (size_t)p * DIM);
#pragma unroll
        for (int q = 0; q < 8; ++q) {
            float4 a = xr[q];
            xi[4 * q] = a.x; xi[4 * q + 1] = a.y; xi[4 * q + 2] = a.z; xi[4 * q + 3] = a.w;
        }
    }
    float nxp = nx[p];

    const float* row = cxf + (size_t)jb * CXS;
    float S = 0.f;
    for (int jj = 0; jj < 256; ++jj) {
        float a0 = 0.f, a1 = 0.f, a2 = 0.f, a3 = 0.f;
#pragma unroll
        for (int q = 0; q < 8; ++q) {
            float4 cv = ((const float4*)row)[q];
            a0 = fmaf(xi[4 * q + 0], cv.x, a0);
            a1 = fmaf(xi[4 * q + 1], cv.y, a1);
            a2 = fmaf(xi[4 * q + 2], cv.z, a2);
            a3 = fmaf(xi[4 * q + 3], cv.w, a3);
        }
        float ncj = row[64];
        float kadd = (row[65] > 0.5f) ? 0.f : -1e38f;
        float sq = fmaxf(fmaf(-2.f, (a0 + a1) + (a2 + a3), nxp + ncj), 0.f);
        float r0 = __builtin_amdgcn_sqrtf(sq + 1e-12f);
        S += __builtin_amdgcn_exp2f(fmaf(r0, -LOG2E, kadd));
        row += CXS;
    }
    ps[(size_t)js * NPTS + p] = S;
}

// ---------------- assignment pass 2: 2 j's per lane, x-rows broadcast ----------------
// grid 1024 = 64 p-tiles(128) x 16 j-tiles(512). block 256 = 4 waves x 64 lanes x 2 j.
__global__ __launch_bounds__(256) void k_apass2(const float* __restrict__ x,
                                                const float* __restrict__ c,
                                                const float* __restrict__ keepf,
                                                const float* __restrict__ ps,
                                                float* __restrict__ A) {
    __shared__ float snx[128];
    __shared__ float sscale[128];
    int t = threadIdx.x;
    int wv = __builtin_amdgcn_readfirstlane(t >> 6);
    int lane = t & 63;
    int pt = (int)blockIdx.x >> 4, jt = (int)blockIdx.x & 15;
    int p0 = pt * 128, j0 = jt * 512;

    if (t < 128) {   // per-row norm + softmax scale
        const float4* xr = (const float4*)(x + (size_t)(p0 + t) * DIM);
        float s = 0.f;
#pragma unroll
        for (int q = 0; q < 8; ++q) {
            float4 v = xr[q];
            s += v.x * v.x + v.y * v.y + v.z * v.z + v.w * v.w;
        }
        snx[t] = s;
        float SS = 0.f;
        for (int js = 0; js < 32; ++js) SS += ps[(size_t)js * NPTS + p0 + t];
        sscale[t] = 1.f / SS;
    }

    int ja = j0 + wv * 64 + lane;
    int jbx = ja + 256;
    float cj0[DIM], cj1[DIM];
    float nc0 = 0.f, nc1 = 0.f;
    {
        const float4* cra = (const float4*)(c + (size_t)ja * DIM);
        const float4* crb = (const float4*)(c + (size_t)jbx * DIM);
#pragma unroll
        for (int q = 0; q < 8; ++q) {
            float4 va = cra[q], vb = crb[q];
            cj0[4 * q] = va.x; cj0[4 * q + 1] = va.y; cj0[4 * q + 2] = va.z; cj0[4 * q + 3] = va.w;
            cj1[4 * q] = vb.x; cj1[4 * q + 1] = vb.y; cj1[4 * q + 2] = vb.z; cj1[4 * q + 3] = vb.w;
            nc0 += va.x * va.x + va.y * va.y + va.z * va.z + va.w * va.w;
            nc1 += vb.x * vb.x + vb.y * vb.y + vb.z * vb.z + vb.w * vb.w;
        }
    }
    float kadd0 = (keepf[ja] > 0.5f) ? 0.f : -1e38f;
    float kadd1 = (keepf[jbx] > 0.5f) ? 0.f : -1e38f;
    __syncthreads();

    const float* xrow = x + (size_t)p0 * DIM;
    for (int pp = 0; pp < 128; ++pp) {
        float d0 = 0.f, d1 = 0.f, d2 = 0.f, d3 = 0.f;
        float e0 = 0.f, e1 = 0.f, e2 = 0.f, e3 = 0.f;
#pragma unroll
        for (int q = 0; q < 8; ++q) {
            float4 v = ((const float4*)xrow)[q];
            d0 = fmaf(cj0[4 * q + 0], v.x, d0);
            d1 = fmaf(cj0[4 * q + 1], v.y, d1);
            d2 = fmaf(cj0[4 * q + 2], v.z, d2);
            d3 = fmaf(cj0[4 * q + 3], v.w, d3);
            e0 = fmaf(cj1[4 * q + 0], v.x, e0);
            e1 = fmaf(cj1[4 * q + 1], v.y, e1);
            e2 = fmaf(cj1[4 * q + 2], v.z, e2);
            e3 = fmaf(cj1[4 * q + 3], v.w, e3);
        }
        float nxp = snx[pp], scl = sscale[pp];
        float sqa = fmaxf(fmaf(-2.f, (d0 + d1) + (d2 + d3), nxp + nc0), 0.f);
        float sqb = fmaxf(fmaf(-2.f, (e0 + e1) + (e2 + e3), nxp + nc1), 0.f);
        float ra = __builtin_amdgcn_sqrtf(sqa + 1e-12f);
        float rb = __builtin_amdgcn_sqrtf(sqb + 1e-12f);
        float ta = fmaf(ra, -LOG2E, kadd0);
        float tb = fmaf(rb, -LOG2E, kadd1);
        float* rowp = A + (size_t)(p0 + pp) * NPTS;
        rowp[ja] = __builtin_amdgcn_exp2f(ta) * scl;
        rowp[jbx] = __builtin_amdgcn_exp2f(tb) * scl;
        xrow += DIM;
    }
}

extern "C" void kernel_launch(void* const* d_in, const int* in_sizes, int n_in,
                              void* d_out, int out_size, void* d_ws, size_t ws_size,
                              hipStream_t stream) {
    const float* x = (const float*)d_in[0];
    const float* sigma = (const float*)d_in[1];

    float* out = (float*)d_out;
    float* OUT_C = out;                          // NPTS*DIM
    float* A = out + (size_t)NPTS * DIM;         // NPTS*NPTS
    float* OUT_K = A + (size_t)NPTS * NPTS;      // NPTS

    float* msP = A + OFF_MSP;
    float* cxf = A + OFF_CXF;
    float* c_new = A + OFF_CNEW;
    float* nx = A + OFF_NX;
    float* pv = A + OFF_PV;
    int* pj = (int*)(A + OFF_PJ);
    int* rkp = (int*)(A + OFF_RKP);
    unsigned int* msh = (unsigned int*)(A + OFF_MSH);
    int* scores = (int*)(A + OFF_SCO);
    int* order = (int*)(A + OFF_ORD);
    float* ps = (float*)d_ws;                    // 1 MB, survives apass2

    k_init<<<NPTS / 256, 256, 0, stream>>>(x, cxf, nx, scores, msh);
    for (int itr = 0; itr < MAX_ITER; ++itr) {
        k_ms2<<<1024, 256, 0, stream>>>(x, nx, cxf, sigma, msP);
        k_reduce<<<NPTS / 256, 256, 0, stream>>>(msP, cxf, c_new, msh + itr);
        k_update<<<NPTS / 256, 256, 0, stream>>>(cxf, c_new, msh + itr);
    }
    k_extract<<<NPTS * 8 / 256, 256, 0, stream>>>(cxf, OUT_C);

    k_scores2<<<1024, 256, 0, stream>>>(x, nx, cxf, pv, pj);
    k_score_comb<<<NPTS / 256, 256, 0, stream>>>(pv, pj, scores);
    k_rank_part<<<1024, 256, 0, stream>>>(scores, rkp);
    k_rank_comb<<<NPTS / 256, 256, 0, stream>>>(rkp, order);
    k_nms<<<1, 1024, 0, stream>>>(OUT_C, order, scores, sigma, OUT_K, cxf);

    k_apass1<<<1024, 256, 0, stream>>>(x, nx, cxf, ps);
    k_apass2<<<1024, 256, 0, stream>>>(x, OUT_C, OUT_K, ps, A);
}